// Round 13
// baseline (107.131 us; speedup 1.0000x reference)
//
#include <hip/hip_runtime.h>
#include <hip/hip_bf16.h>

#define NB 16
#define NC 128
#define NN 2048
#define NF 64
#define NEG_SLOPE 0.33f
#define EXP_K 1.4426950408889634f   // log2(e): pre-scale so exp() is exp2()

typedef float    f32x2 __attribute__((ext_vector_type(2)));
typedef float    f32x4 __attribute__((ext_vector_type(4)));
typedef _Float16 f16x2 __attribute__((ext_vector_type(2)));
typedef _Float16 f16x4 __attribute__((ext_vector_type(4)));
typedef _Float16 f16x8 __attribute__((ext_vector_type(8)));

__device__ __forceinline__ float lrelu(float x) {
    return fmaxf(x, x * NEG_SLOPE);   // valid leaky-relu for slope<1; commutes with positive scaling
}

// Kernel 1: Wh = h^T @ W in fp32 (VALU, LDS-tiled); emit WhT f16 [b][f][n],
// s1 = Wh@a1, s2 = Wh@a2 in fp32.  (unchanged)
__global__ __launch_bounds__(256) void k_precompute(
    const float* __restrict__ h, const float* __restrict__ W,
    const float* __restrict__ a, _Float16* __restrict__ wht,
    float* __restrict__ s1g, float* __restrict__ s2g)
{
    __shared__ float Wl[64 * 64];
    __shared__ float ht[64 * 129];

    const int t = threadIdx.x;
    const int b = blockIdx.x >> 5;
    const int n0 = (blockIdx.x & 31) << 6;
    const int lane = t & 63, cg = t >> 6;

    #pragma unroll 8
    for (int k = 0; k < 32; ++k) {
        const int c = cg * 32 + k;
        ht[lane * 129 + c] = h[(size_t)(b * NC + c) * NN + n0 + lane];
    }

    const int fg = t & 15, ns = t >> 4;
    f32x4 acc[4] = {};
    for (int half = 0; half < 2; ++half) {
        if (half) __syncthreads();
        #pragma unroll
        for (int k = 0; k < 4; ++k) {
            const int idx = k * 1024 + t * 4;
            *(f32x4*)&Wl[idx] = *(const f32x4*)&W[half * 4096 + idx];
        }
        __syncthreads();
        #pragma unroll 4
        for (int c2 = 0; c2 < 64; ++c2) {
            const f32x4 wv = *(const f32x4*)&Wl[c2 * 64 + fg * 4];
            #pragma unroll
            for (int m = 0; m < 4; ++m) {
                const float hv = ht[(ns * 4 + m) * 129 + half * 64 + c2];
                acc[m] += wv * hv;
            }
        }
    }

    const f32x4 a1v = *(const f32x4*)&a[fg * 4];
    const f32x4 a2v = *(const f32x4*)&a[NF + fg * 4];
    #pragma unroll
    for (int m = 0; m < 4; ++m) {
        float p1 = acc[m].x * a1v.x + acc[m].y * a1v.y + acc[m].z * a1v.z + acc[m].w * a1v.w;
        float p2 = acc[m].x * a2v.x + acc[m].y * a2v.y + acc[m].z * a2v.z + acc[m].w * a2v.w;
        #pragma unroll
        for (int d = 1; d < 16; d <<= 1) {
            p1 += __shfl_xor(p1, d, 64);
            p2 += __shfl_xor(p2, d, 64);
        }
        if (fg == 0) {
            const int n = n0 + ns * 4 + m;
            s1g[(size_t)b * NN + n] = p1;
            s2g[(size_t)b * NN + n] = p2;
        }
    }
    #pragma unroll
    for (int q = 0; q < 4; ++q) {
        f16x4 v;
        v[0] = (_Float16)acc[0][q]; v[1] = (_Float16)acc[1][q];
        v[2] = (_Float16)acc[2][q]; v[3] = (_Float16)acc[3][q];
        const int f = fg * 4 + q;
        *(f16x4*)&wht[((size_t)b * NF + f) * NN + n0 + ns * 4] = v;
    }
}

// Kernel 2: two-phase fused GAT.
// PHASE 1 (dense stream): block owns a CONTIGUOUS 256 KB g-slab (32 rows).
//   Wave w streams rows w*8..w*8+7 sequentially, full 8 KB per row, packing
//   g>0 into LDS mask bytes (bit j of mb[row][cbyte] = col cbyte*8+j > 0).
//   Chip-wide: 1024 dense sequential slab streams (fillBuffer-like), not the
//   previous 64K fine-grained 256B-touch row streams — the R2..R11 plateau.
// PHASE 2 (mask-driven, zero HBM): R11's MFMA structure; P from mask bits +
//   fixed bound-shift exp2; wht from XCD-pinned L2; ones-MFMA exact row sums.
// Blocks stagger phases across the 4 blocks/CU -> HBM stays saturated.
//
// GRID CONTRACT (R4/R7 bug class): decode is p = (hi<<9)|(strip<<3)|xcd with
// hi in [0,2), strip in [0,64), xcd in [0,8)  ==> grid MUST be 2*64*8 = 1024.
#define K2_N_HI    2
#define K2_N_STRIP 64
#define K2_N_XCD   8
#define MB_STRIDE  264            // mask row stride (bytes): 264%128=8 -> banks spread
__global__ __launch_bounds__(256) void k_attn(
    const float* __restrict__ g, const _Float16* __restrict__ wht,
    const float* __restrict__ s1g, const float* __restrict__ s2g,
    float* __restrict__ out)
{
    __shared__ float s2b[NN];                        // 8 KB (pre-scaled by log2 e)
    __shared__ float s1b[32];
    __shared__ float wred[4];
    __shared__ unsigned char mb[32 * MB_STRIDE];     // 8.25 KB mask bytes
    __shared__ __align__(16) _Float16 Pc[4][1024];   // per-wave 16 rows x 64 f16 (2 KB each)
    __shared__ f32x4 accS[2][5][64];                 // jq=1 partials: [rg][acc0..3,sums][lane]

    const int t = threadIdx.x;
    const int lane = t & 63;
    const int w = t >> 6;                            // wave 0..3
    const int rg = w & 1, jq = w >> 1;               // row-group, j-half (phase 2 roles)

    // XCD-pinned decode (bijective over the 1024-block grid)
    const int p = blockIdx.x;
    const int b = (p & 7) + ((p >> 9) << 3);
    const int strip = (p >> 3) & 63;
    const int i0 = strip * 32;                       // block's first row (32 rows)

    // ---- prologue: scaled s2 -> LDS, s1 tile, per-wave max(s2) ----
    f32x4 sA = *(const f32x4*)&s2g[(size_t)b * NN + t * 8];
    f32x4 sB = *(const f32x4*)&s2g[(size_t)b * NN + t * 8 + 4];
    sA *= EXP_K; sB *= EXP_K;
    *(f32x4*)&s2b[t * 8] = sA;
    *(f32x4*)&s2b[t * 8 + 4] = sB;
    if (t < 32) s1b[t] = s1g[(size_t)b * NN + i0 + t] * EXP_K;
    float lm = fmaxf(fmaxf(fmaxf(sA.x, sA.y), fmaxf(sA.z, sA.w)),
                     fmaxf(fmaxf(sB.x, sB.y), fmaxf(sB.z, sB.w)));
    #pragma unroll
    for (int d = 1; d < 64; d <<= 1) lm = fmaxf(lm, __shfl_xor(lm, d, 64));
    if (lane == 0) wred[w] = lm;

    // ---- PHASE 1: dense sequential slab stream -> mask bits in LDS ----
    // wave w: rows w*8 .. w*8+7; per row: lane covers 8 consecutive f32 at
    // k*512 + lane*8 (k=0..3) -> one mask byte mb[row][k*64+lane] per k.
    {
        const float* gbase = g + (size_t)b * NN * NN + (size_t)i0 * NN;
        #pragma unroll 1
        for (int it = 0; it < 8; ++it) {
            const int br = w * 8 + it;
            const float* rowp = gbase + (size_t)br * NN + lane * 8;
            unsigned bm[4];
            #pragma unroll
            for (int k = 0; k < 4; ++k) {
                const f32x4 va = *(const f32x4*)(rowp + k * 512);
                const f32x4 vb = *(const f32x4*)(rowp + k * 512 + 4);
                unsigned m = 0;
                m |= (va.x > 0.0f) ? 1u   : 0u;
                m |= (va.y > 0.0f) ? 2u   : 0u;
                m |= (va.z > 0.0f) ? 4u   : 0u;
                m |= (va.w > 0.0f) ? 8u   : 0u;
                m |= (vb.x > 0.0f) ? 16u  : 0u;
                m |= (vb.y > 0.0f) ? 32u  : 0u;
                m |= (vb.z > 0.0f) ? 64u  : 0u;
                m |= (vb.w > 0.0f) ? 128u : 0u;
                bm[k] = m;
            }
            #pragma unroll
            for (int k = 0; k < 4; ++k)
                mb[br * MB_STRIDE + k * 64 + lane] = (unsigned char)bm[k];
        }
    }

    __syncthreads();   // s2b, s1b, wred, mb all visible to all waves

    const float S2MAX = fmaxf(fmaxf(wred[0], wred[1]), fmaxf(wred[2], wred[3]));

    // ---- PHASE 2: mask-driven flash-GAT (no HBM in the loop) ----
    // lane: l15 = P-row within row-group AND wht feature col; l4 = col-group/k-group
    const int l15 = lane & 15, l4 = lane >> 4;
    const float s1r = s1b[rg * 16 + l15];            // scaled
    const float Mr  = lrelu(s1r + S2MAX);            // scaled upper bound on row scores

    const _Float16* wb = wht + ((size_t)b * NF + l15) * NN + jq * 1024 + l4 * 8;
    char* pcb = (char*)&Pc[w][0];
    const unsigned char* mrow = &mb[(rg * 16 + l15) * MB_STRIDE + jq * 128];
    const float* s2h = &s2b[jq * 1024];
    const unsigned swz = (unsigned)((l15 & 7) << 4); // row-XOR swizzle (bank spread)

    f32x4 acc0 = {0,0,0,0}, acc1 = {0,0,0,0}, acc2 = {0,0,0,0}, acc3 = {0,0,0,0};
    f32x4 acc_s = {0,0,0,0};                         // exact row sums via ones-MFMA
    f16x8 ones;
    #pragma unroll
    for (int u = 0; u < 8; ++u) ones[u] = (_Float16)1.0f;

    #pragma unroll 1
    for (int ch = 0; ch < 16; ++ch) {
        // [1] wht B-frags (L2-resident, XCD-pinned; latency hides under P-gen)
        f16x8 bfv[2][4];
        #pragma unroll
        for (int ks = 0; ks < 2; ++ks) {
            #pragma unroll
            for (int ft = 0; ft < 4; ++ft)
                bfv[ks][ft] = *(const f16x8*)(wb + (size_t)ft * 16 * NN + ch * 64 + ks * 32);
        }
        // [2] P-gen: 16 cols (cg block) of row l15 from mask u16 + s2 tables
        const unsigned bits = *(const unsigned short*)(mrow + ch * 8 + l4 * 2);
        const float* sc = s2h + ch * 64 + l4 * 16;
        const f32x4 sv0 = *(const f32x4*)(sc);
        const f32x4 sv1 = *(const f32x4*)(sc + 4);
        const f32x4 sv2 = *(const f32x4*)(sc + 8);
        const f32x4 sv3 = *(const f32x4*)(sc + 12);
        f16x8 pa, pb;
        #pragma unroll
        for (int e = 0; e < 4; ++e) {
            pa[e]     = (bits >> e        & 1u) ? (_Float16)__builtin_amdgcn_exp2f(lrelu(s1r + sv0[e]) - Mr) : (_Float16)0.0f;
            pa[e + 4] = (bits >> (e + 4)  & 1u) ? (_Float16)__builtin_amdgcn_exp2f(lrelu(s1r + sv1[e]) - Mr) : (_Float16)0.0f;
            pb[e]     = (bits >> (e + 8)  & 1u) ? (_Float16)__builtin_amdgcn_exp2f(lrelu(s1r + sv2[e]) - Mr) : (_Float16)0.0f;
            pb[e + 4] = (bits >> (e + 12) & 1u) ? (_Float16)__builtin_amdgcn_exp2f(lrelu(s1r + sv3[e]) - Mr) : (_Float16)0.0f;
        }
        *(f16x8*)(pcb + ((unsigned)(l15 * 128 + l4 * 32)      ^ swz)) = pa;
        *(f16x8*)(pcb + ((unsigned)(l15 * 128 + l4 * 32 + 16) ^ swz)) = pb;
        // [3] A-frags (same-wave lgkmcnt ordering; no barrier) + 10 MFMA
        #pragma unroll
        for (int ks = 0; ks < 2; ++ks) {
            const f16x8 af = *(const f16x8*)(pcb +
                ((unsigned)(l15 * 128 + ks * 64 + l4 * 16) ^ swz));
            acc0  = __builtin_amdgcn_mfma_f32_16x16x32_f16(af, bfv[ks][0], acc0, 0, 0, 0);
            acc1  = __builtin_amdgcn_mfma_f32_16x16x32_f16(af, bfv[ks][1], acc1, 0, 0, 0);
            acc2  = __builtin_amdgcn_mfma_f32_16x16x32_f16(af, bfv[ks][2], acc2, 0, 0, 0);
            acc3  = __builtin_amdgcn_mfma_f32_16x16x32_f16(af, bfv[ks][3], acc3, 0, 0, 0);
            acc_s = __builtin_amdgcn_mfma_f32_16x16x32_f16(af, ones,       acc_s, 0, 0, 0);
        }
    }

    // ---- epilogue: combine j-half partials (additive under fixed shift), normalize, store ----
    if (jq == 1) {
        accS[rg][0][lane] = acc0;
        accS[rg][1][lane] = acc1;
        accS[rg][2][lane] = acc2;
        accS[rg][3][lane] = acc3;
        accS[rg][4][lane] = acc_s;
    }
    __syncthreads();
    if (jq == 0) {
        acc0  += accS[rg][0][lane];
        acc1  += accS[rg][1][lane];
        acc2  += accS[rg][2][lane];
        acc3  += accS[rg][3][lane];
        acc_s += accS[rg][4][lane];
        f32x4 rinv;
        #pragma unroll
        for (int q = 0; q < 4; ++q) rinv[q] = 1.0f / acc_s[q];

        const size_t ob = ((size_t)b * NF + l15) * NN + (size_t)(i0 + rg * 16) + l4 * 4;
        f32x4 o0, o1, o2, o3;
        #pragma unroll
        for (int q = 0; q < 4; ++q) {    // D row m = l4*4+q (m89-verified), col = l15
            o0[q] = acc0[q] * rinv[q];
            o1[q] = acc1[q] * rinv[q];
            o2[q] = acc2[q] * rinv[q];
            o3[q] = acc3[q] * rinv[q];
        }
        *(f32x4*)&out[ob]                   = o0;
        *(f32x4*)&out[ob + (size_t)16 * NN] = o1;
        *(f32x4*)&out[ob + (size_t)32 * NN] = o2;
        *(f32x4*)&out[ob + (size_t)48 * NN] = o3;
    }
}

extern "C" void kernel_launch(void* const* d_in, const int* in_sizes, int n_in,
                              void* d_out, int out_size, void* d_ws, size_t ws_size,
                              hipStream_t stream)
{
    (void)in_sizes; (void)n_in; (void)out_size; (void)ws_size;
    const float* h = (const float*)d_in[0];
    const float* g = (const float*)d_in[1];
    const float* W = (const float*)d_in[2];
    const float* a = (const float*)d_in[3];
    float* out = (float*)d_out;

    // workspace: WhT f16 (4 MiB) | s1 (128 KiB) | s2 (128 KiB)
    char* ws = (char*)d_ws;
    _Float16* wht = (_Float16*)ws;
    float* s1 = (float*)(ws + (size_t)NB * NF * NN * sizeof(_Float16));
    float* s2 = s1 + (size_t)NB * NN;

    k_precompute<<<NB * (NN / 64), 256, 0, stream>>>(h, W, a, wht, s1, s2);
    // grid derived from the decode's factor sizes — R4/R7 bug class guard
    k_attn<<<K2_N_HI * K2_N_STRIP * K2_N_XCD, 256, 0, stream>>>(g, wht, s1, s2, out);
}